// Round 7
// baseline (13.784 us; speedup 1.0000x reference)
//
#include <hip/hip_runtime.h>
#include <math.h>

// features: (B=8, C=64, L=8192) fp32; H=32, UNIT=512, W=544
// out[b,h,l] = corr(col l, col l+1+h) within block n=l/512
#define CC    64
#define LL    8192
#define HH    32
#define UNITL 512
#define TC    64          // output columns per workgroup (1/8 window)
#define WC    96          // TC + 32 halo; 6 row-blocks of 16
#define STR   98          // fp32 row stride: 98%4==2 -> k-group column reads
                          // alternate 16-bank halves (max 2-way conflict = free)
#define BSTR  68          // band row stride (floats)
#define EPSF  1e-12f

typedef __attribute__((ext_vector_type(8))) short bf16x8;
typedef __attribute__((ext_vector_type(4))) float f32x4;
typedef __attribute__((ext_vector_type(2))) float f32x2;

// LDS (25,088 B -> 4 blocks/CU with room to spare):
//   u.xs  : fp32 window [64][98]                  25,088 B (phases 1-2)
//   u.s   : band[32][68] + ms[96] + ns[96]         9,472 B (phases 3-4, reuse)
union U {
    float xs[CC][STR];
    struct {
        float band[HH][BSTR];
        float ms[WC];
        float ns[WC];
    } s;
};

__device__ __forceinline__ unsigned rne_bf16(unsigned ub) {
    return (ub + 0x7FFFu + ((ub >> 16) & 1u)) >> 16;   // RNE f32->bf16 (finite)
}

__global__ __launch_bounds__(256, 4)
void tsm_kernel(const float* __restrict__ feat, float* __restrict__ out) {
    __shared__ U u;

    const int tid  = threadIdx.x;
    const int lane = tid & 63;
    const int wv   = tid >> 6;            // 0..3
    const int blk  = blockIdx.x;          // 0..1023
    const int q8   = blk & 7;
    const int n    = (blk >> 3) & 15;
    const int b    = blk >> 7;
    const int col0 = n * UNITL + q8 * TC;

    const float* fb = feat + (size_t)b * CC * LL;

    // ---- phase 1: stage fp32 window, coalesced f32x4 loads (zero past L) ----
    #pragma unroll
    for (int it = 0; it < 6; ++it) {
        int tau = it * 256 + tid;          // 0..1535  (64 rows x 24 f32x4)
        int c   = tau / 24;
        int q   = tau - c * 24;
        int l   = col0 + 4 * q;
        f32x4 v = {0.f, 0.f, 0.f, 0.f};
        if (l < LL) v = *reinterpret_cast<const f32x4*>(fb + (size_t)c * LL + l);
        // STR is not a multiple of 4 -> 8B-aligned writes only
        *reinterpret_cast<f32x2*>(&u.xs[c][4 * q])     = (f32x2){v[0], v[1]};
        *reinterpret_cast<f32x2*>(&u.xs[c][4 * q + 2]) = (f32x2){v[2], v[3]};
    }
    __syncthreads();

    // ---- phase 2: frag assembly via column reads + in-reg bf16 split; stats ----
    const int r16 = lane & 15;
    const int g   = lane >> 4;
    bf16x8 fh[3][2], fl[3][2];
    #pragma unroll
    for (int bb = 0; bb < 3; ++bb) {
        int row = 16 * (wv + bb) + r16;    // <= 95
        #pragma unroll
        for (int kk = 0; kk < 2; ++kk) {
            int cb = 8 * g + 32 * kk;      // k-slice -> channel base
            #pragma unroll
            for (int j = 0; j < 8; ++j) {
                float x = u.xs[cb + j][row];
                unsigned ub = __float_as_uint(x);
                unsigned hr = rne_bf16(ub);
                float lo = x - __uint_as_float(hr << 16);   // exact
                unsigned lr = rne_bf16(__float_as_uint(lo));
                fh[bb][kk][j] = (short)hr;
                fl[bb][kk][j] = (short)lr;
            }
        }
    }
    float m = 0.f, nr = 0.f;
    if (tid < WC) {                        // stats: conflict-free column reads
        float s = 0.f, ss = 0.f;
        #pragma unroll
        for (int c = 0; c < CC; ++c) { float x = u.xs[c][tid]; s += x; ss += x * x; }
        m  = s * (1.0f / CC);
        nr = sqrtf(fmaxf(ss - (float)CC * m * m, 0.f));
    }
    __syncthreads();                       // xs dead; union area becomes band/stats

    // ---- phase 3: MFMA banded Gram + scatter; stats write ----
    if (tid < WC) { u.s.ms[tid] = m; u.s.ns[tid] = nr; }
    #pragma unroll
    for (int dj = 0; dj < 3; ++dj) {
        f32x4 acc = {0.f, 0.f, 0.f, 0.f};
        acc = __builtin_amdgcn_mfma_f32_16x16x32_bf16(fh[0][0], fh[dj][0], acc, 0, 0, 0);
        acc = __builtin_amdgcn_mfma_f32_16x16x32_bf16(fh[0][1], fh[dj][1], acc, 0, 0, 0);
        acc = __builtin_amdgcn_mfma_f32_16x16x32_bf16(fh[0][0], fl[dj][0], acc, 0, 0, 0);
        acc = __builtin_amdgcn_mfma_f32_16x16x32_bf16(fh[0][1], fl[dj][1], acc, 0, 0, 0);
        acc = __builtin_amdgcn_mfma_f32_16x16x32_bf16(fl[0][0], fh[dj][0], acc, 0, 0, 0);
        acc = __builtin_amdgcn_mfma_f32_16x16x32_bf16(fl[0][1], fh[dj][1], acc, 0, 0, 0);
        // C/D (m89-verified): col = lane&15 -> tp; row = 4*(lane>>4)+reg -> t
        #pragma unroll
        for (int r = 0; r < 4; ++r) {
            int t  = 16 * wv + 4 * g + r;          // 0..63
            int tp = 16 * (wv + dj) + r16;         // 0..95
            int h  = tp - t - 1;
            if ((unsigned)h < 32u) u.s.band[h][t] = acc[r];
        }
    }
    __syncthreads();

    // ---- phase 4: normalize + mask + coalesced f32x4 store ----
    {
        const int h   = tid >> 3;                  // 0..31
        const int cb8 = tid & 7;
        float* ob = out + ((size_t)b * HH + h) * LL + col0;
        #pragma unroll
        for (int k = 0; k < 2; ++k) {
            int t0 = 4 * (cb8 + 8 * k);            // 0..60
            f32x4 v = *reinterpret_cast<const f32x4*>(&u.s.band[h][t0]);
            f32x4 res;
            #pragma unroll
            for (int e = 0; e < 4; ++e) {
                int t  = t0 + e;
                int tp = t + 1 + h;                // <= 95
                float num  = v[e] - (float)CC * u.s.ms[t] * u.s.ms[tp];
                float den  = fmaxf(u.s.ns[t] * u.s.ns[tp], EPSF);
                float corr = num * __builtin_amdgcn_rcpf(den);
                if (col0 + tp >= LL) corr = 0.f;   // reference band mask
                res[e] = corr;
            }
            *reinterpret_cast<f32x4*>(ob + t0) = res;
        }
    }
}

extern "C" void kernel_launch(void* const* d_in, const int* in_sizes, int n_in,
                              void* d_out, int out_size, void* d_ws, size_t ws_size,
                              hipStream_t stream) {
    const float* feat = (const float*)d_in[0];
    float* out = (float*)d_out;
    // 1024 blocks = B(8) x n(16) x eighths(8); 256 threads; 4 blocks/CU.
    tsm_kernel<<<dim3(1024), dim3(256), 0, stream>>>(feat, out);
}